// Round 2
// 2334.453 us; speedup vs baseline: 1.0893x; 1.0893x over previous
//
#include <hip/hip_runtime.h>
#include <stdint.h>

#define BATCH    8192
#define NEXP     8
#define DIN      2048
#define DHID     8192
#define DOUT     2048
#define MAXTILES 136
#define SLOTCAP  (MAXTILES * 128)   /* 17408 */
#define ZROW     BATCH              /* zero row index in xb */
#define CNTSTR   8                  /* per-expert counter stride (ints) = 32 B; footprint matches r0 layout */

typedef unsigned short u16;
typedef __attribute__((ext_vector_type(8))) __bf16 bf16x8;
typedef __attribute__((ext_vector_type(4))) float  f32x4;

// ---------------- helpers ----------------

__device__ __forceinline__ u16 f2b(float f) {
    union { float f; uint32_t u; } v; v.f = f;
    return (u16)((v.u + 0x7fffu + ((v.u >> 16) & 1u)) >> 16);   // RNE
}
__device__ __forceinline__ float b2f(u16 h) {
    union { uint32_t u; float f; } v; v.u = ((uint32_t)h) << 16; return v.f;
}
__device__ __forceinline__ uint32_t pack2(float a, float b) {
    return (uint32_t)f2b(a) | ((uint32_t)f2b(b) << 16);
}
__device__ __forceinline__ void load_lds16(const void* g, void* l) {
    __builtin_amdgcn_global_load_lds(
        (const __attribute__((address_space(1))) void*)g,
        (__attribute__((address_space(3))) void*)l, 16, 0, 0);
}

// ---------------- router: one wave per token (4 tokens/wave) ----------------
// + fused x fp32->bf16 conversion (this block's 16 rows)
// + LDS histogram -> 8 global atomics per block (kills same-line atomic serialization)

__global__ __launch_bounds__(256) void router_kernel(
    const float* __restrict__ x, const float* __restrict__ gw,
    int* __restrict__ toke, float* __restrict__ tokw, int* __restrict__ counts,
    u16* __restrict__ xb)
{
    __shared__ float g[NEXP * DIN];   // 64 KB
    __shared__ int hist[NEXP];
    const int tid = threadIdx.x;
    if (tid < NEXP) hist[tid] = 0;
    const float4* gsrc = (const float4*)gw;
    float4* gdst = (float4*)g;
    for (int i = tid; i < NEXP * DIN / 4; i += 256) gdst[i] = gsrc[i];

    // fused x -> bf16 for this block's 16 rows (16*2048/8 = 4096 chunks)
    {
        const size_t rowbase = (size_t)blockIdx.x * 16 * DIN;
        for (int ch = tid; ch < 4096; ch += 256) {
            const float* src = x + rowbase + (size_t)ch * 8;
            float4 v0 = *(const float4*)src;
            float4 v1 = *(const float4*)(src + 4);
            uint4 o;
            o.x = pack2(v0.x, v0.y); o.y = pack2(v0.z, v0.w);
            o.z = pack2(v1.x, v1.y); o.w = pack2(v1.z, v1.w);
            *(uint4*)(xb + rowbase + (size_t)ch * 8) = o;
        }
        if (blockIdx.x == 0) {   // zero row (gather target for padded slots)
            uint4 z; z.x = 0u; z.y = 0u; z.z = 0u; z.w = 0u;
            *(uint4*)(xb + (size_t)ZROW * DIN + (size_t)tid * 8) = z;
        }
    }
    __syncthreads();

    const int w = tid >> 6, l = tid & 63;
    for (int it = 0; it < 4; ++it) {
        const int t = blockIdx.x * 16 + w * 4 + it;
        float a[NEXP];
#pragma unroll
        for (int e = 0; e < NEXP; ++e) a[e] = 0.f;
        const float* xr = x + (size_t)t * DIN;
        for (int j = l; j < DIN; j += 64) {
            float xv = xr[j];
#pragma unroll
            for (int e = 0; e < NEXP; ++e) a[e] += xv * g[e * DIN + j];
        }
#pragma unroll
        for (int e = 0; e < NEXP; ++e) {
#pragma unroll
            for (int off = 32; off > 0; off >>= 1)
                a[e] += __shfl_down(a[e], off, 64);
        }
        if (l == 0) {
            int e0 = 0; float v0 = a[0];
            for (int e = 1; e < NEXP; ++e) if (a[e] > v0) { v0 = a[e]; e0 = e; }
            int e1 = -1; float v1 = -3.0e38f;
            for (int e = 0; e < NEXP; ++e) if (e != e0 && a[e] > v1) { v1 = a[e]; e1 = e; }
            float z = expf(v1 - v0);            // <= 1, stable
            float p0 = 1.f / (1.f + z);
            float p1 = z * p0;
            toke[2 * t]     = e0; toke[2 * t + 1] = e1;
            tokw[2 * t]     = p0; tokw[2 * t + 1] = p1;
            atomicAdd(&hist[e0], 1);            // LDS, on-CU
            atomicAdd(&hist[e1], 1);
        }
    }
    __syncthreads();
    if (tid < NEXP) atomicAdd(&counts[tid * CNTSTR], hist[tid]);   // 8 per block, spread lines
}

// ---------------- fp32 -> bf16 weight converter ----------------

__global__ __launch_bounds__(256) void convert_w_kernel(
    const float* __restrict__ src, u16* __restrict__ dst)
{
    const size_t base = ((size_t)blockIdx.x * 256 + threadIdx.x) * 8;
    float4 v0 = *(const float4*)(src + base);
    float4 v1 = *(const float4*)(src + base + 4);
    uint4 o;
    o.x = pack2(v0.x, v0.y); o.y = pack2(v0.z, v0.w);
    o.z = pack2(v1.x, v1.y); o.w = pack2(v1.z, v1.w);
    *(uint4*)(dst + base) = o;
}

// ---------------- plan: segments (128-padded), tile map, init ----------------

__global__ __launch_bounds__(256) void plan_kernel(
    const int* __restrict__ counts, int* __restrict__ seg,
    int* __restrict__ tile_e, int* __restrict__ tile_r,
    int* __restrict__ curs, int* __restrict__ slottok)
{
    const int tid = threadIdx.x;
    for (int s = tid; s < SLOTCAP; s += 256) slottok[s] = ZROW;  // pads gather zero row
    if (tid == 0) {
        int off = 0, ctr = 0;
        for (int e = 0; e < NEXP; ++e) {
            seg[e] = off;
            curs[e * CNTSTR] = 0;
            int tiles = (counts[e * CNTSTR] + 127) >> 7;
            for (int i = 0; i < tiles; ++i) { tile_e[ctr] = e; tile_r[ctr] = off + i * 128; ++ctr; }
            off += tiles * 128;
        }
        for (; ctr < MAXTILES; ++ctr) { tile_e[ctr] = -1; tile_r[ctr] = 0; }
    }
}

// ---------------- scatter: per-block LDS aggregation, 8 global atomic-returns/block ----------------

__global__ __launch_bounds__(256) void scatter_kernel(
    const int* __restrict__ toke, int* __restrict__ curs, const int* __restrict__ seg,
    int* __restrict__ slottok, int* __restrict__ tslot)
{
    __shared__ int lh[NEXP];      // block-local per-expert count
    __shared__ int lbase[NEXP];   // this block's base offset within expert segment
    const int tid = threadIdx.x;
    const int t = blockIdx.x * 256 + tid;
    if (tid < NEXP) lh[tid] = 0;
    __syncthreads();
    const int e0 = toke[2 * t], e1 = toke[2 * t + 1];
    const int p0 = atomicAdd(&lh[e0], 1);     // LDS atomics: on-CU, fast
    const int p1 = atomicAdd(&lh[e1], 1);
    __syncthreads();
    if (tid < NEXP) lbase[tid] = atomicAdd(&curs[tid * CNTSTR], lh[tid]);  // 8/block
    __syncthreads();
    const int s0 = seg[e0] + lbase[e0] + p0;
    const int s1 = seg[e1] + lbase[e1] + p1;
    slottok[s0] = t;
    slottok[s1] = t;
    tslot[2 * t]     = s0;
    tslot[2 * t + 1] = s1;
}

// ---------------- m97-style bf16 NT GEMM: C[M,N] = A[M,K] . W[N,K]^T ----------------
// 128x128 tile, BK=64, 4 waves x (4x4) mfma_f32_16x16x32_bf16, global_load_lds(16B),
// XOR-swizzled 16B chunks in LDS (2-way bank aliasing only).

template<int KDIM, int NDIM, bool PHASE1>
__global__ __launch_bounds__(256, 2) void gemm_kernel(
    const u16* __restrict__ Abase,   // PHASE1: xb (gather via slottok); else: h (direct slot rows)
    const u16* __restrict__ Wbase,   // bf16 weights, all experts, [E][NDIM][KDIM]
    const float* __restrict__ bias,  // [E][NDIM]
    const int* __restrict__ tile_e, const int* __restrict__ tile_r,
    const int* __restrict__ slottok,
    u16* __restrict__ Out)           // PHASE1: h [SLOTCAP][DHID] (gelu applied); else: y [SLOTCAP][DOUT]
{
    const int e = tile_e[blockIdx.y];
    if (e < 0) return;
    const int rowbase = tile_r[blockIdx.y];
    const int n0 = blockIdx.x * 128;

    __shared__ __align__(16) u16 sA[128 * 64];   // 16 KB
    __shared__ __align__(16) u16 sB[128 * 64];   // 16 KB

    const int tid = threadIdx.x;
    const int w = tid >> 6, l = tid & 63;
    const int lr = l & 15, lq = l >> 4;
    const int wm = (w >> 1) * 64, wn = (w & 1) * 64;

    // --- staging addresses (fixed rows, k advances) ---
    const char* aPtr[4]; const char* bPtr[4];
    int ldsOff[4];
#pragma unroll
    for (int i = 0; i < 4; ++i) {
        int g = (w * 4 + i) * 64 + l;       // global 16B-chunk id, 0..1023
        int r = g >> 3, p = g & 7;
        int c = p ^ (r & 7);                // logical k-chunk stored at position p
        ldsOff[i] = g * 8;                  // u16 elements
        size_t arow = PHASE1 ? (size_t)slottok[rowbase + r] : (size_t)(rowbase + r);
        aPtr[i] = (const char*)(Abase + arow * (size_t)KDIM) + c * 16;
        size_t brow = (size_t)e * NDIM + (size_t)(n0 + r);
        bPtr[i] = (const char*)(Wbase + brow * (size_t)KDIM) + c * 16;
    }

    // --- fragment LDS offsets (u16 elements) ---
    int aOff[2][4], bOff[2][4];
#pragma unroll
    for (int s = 0; s < 2; ++s)
#pragma unroll
        for (int i = 0; i < 4; ++i) {
            int rowA = wm + i * 16 + lr;
            aOff[s][i] = rowA * 64 + (((s * 4 + lq) ^ (rowA & 7)) * 8);
            int rowB = wn + i * 16 + lr;
            bOff[s][i] = rowB * 64 + (((s * 4 + lq) ^ (rowB & 7)) * 8);
        }

    f32x4 acc[4][4];
#pragma unroll
    for (int i = 0; i < 4; ++i)
#pragma unroll
        for (int j = 0; j < 4; ++j)
#pragma unroll
            for (int r = 0; r < 4; ++r) acc[i][j][r] = 0.f;

    for (int k0 = 0; k0 < KDIM; k0 += 64) {
        const size_t kb = (size_t)k0 * 2;
#pragma unroll
        for (int i = 0; i < 4; ++i) load_lds16(aPtr[i] + kb, &sA[ldsOff[i]]);
#pragma unroll
        for (int i = 0; i < 4; ++i) load_lds16(bPtr[i] + kb, &sB[ldsOff[i]]);
        __syncthreads();                     // compiler emits vmcnt(0) drain here
#pragma unroll
        for (int s = 0; s < 2; ++s) {
            bf16x8 aF[4], bF[4];
#pragma unroll
            for (int i = 0; i < 4; ++i) aF[i] = *(const bf16x8*)&sA[aOff[s][i]];
#pragma unroll
            for (int j = 0; j < 4; ++j) bF[j] = *(const bf16x8*)&sB[bOff[s][j]];
#pragma unroll
            for (int i = 0; i < 4; ++i)
#pragma unroll
                for (int j = 0; j < 4; ++j)
                    acc[i][j] = __builtin_amdgcn_mfma_f32_16x16x32_bf16(aF[i], bF[j], acc[i][j], 0, 0, 0);
        }
        __syncthreads();
    }

    // --- epilogue: C/D layout col=lane&15, row=(lane>>4)*4+reg ---
    float bv[4];
#pragma unroll
    for (int j = 0; j < 4; ++j) bv[j] = bias[(size_t)e * NDIM + n0 + wn + j * 16 + lr];
#pragma unroll
    for (int i = 0; i < 4; ++i)
#pragma unroll
        for (int j = 0; j < 4; ++j)
#pragma unroll
            for (int r = 0; r < 4; ++r) {
                int grow = rowbase + wm + i * 16 + lq * 4 + r;
                int gcol = n0 + wn + j * 16 + lr;
                float v = acc[i][j][r] + bv[j];
                if (PHASE1) v = 0.5f * v * (1.f + erff(v * 0.70710678118654752f));
                Out[(size_t)grow * NDIM + gcol] = f2b(v);
            }
}

// ---------------- combine: out[t] = w0*y[s0] + w1*y[s1] ----------------

__global__ __launch_bounds__(256) void combine_kernel(
    const u16* __restrict__ y, const int* __restrict__ tslot,
    const float* __restrict__ tokw, float* __restrict__ out)
{
    const int n = blockIdx.x * 256 + threadIdx.x;
    const int t = n >> 8;             // 256 threads per token (2048 cols / 8)
    const int c = (n & 255) << 3;
    const int s0 = tslot[2 * t], s1 = tslot[2 * t + 1];
    const float w0 = tokw[2 * t], w1 = tokw[2 * t + 1];
    uint4 u0 = *(const uint4*)(y + (size_t)s0 * DOUT + c);
    uint4 u1 = *(const uint4*)(y + (size_t)s1 * DOUT + c);
    float* o = out + (size_t)t * DOUT + c;
    float4 r0, r1;
    r0.x = w0 * b2f(u0.x & 0xffff) + w1 * b2f(u1.x & 0xffff);
    r0.y = w0 * b2f(u0.x >> 16)    + w1 * b2f(u1.x >> 16);
    r0.z = w0 * b2f(u0.y & 0xffff) + w1 * b2f(u1.y & 0xffff);
    r0.w = w0 * b2f(u0.y >> 16)    + w1 * b2f(u1.y >> 16);
    r1.x = w0 * b2f(u0.z & 0xffff) + w1 * b2f(u1.z & 0xffff);
    r1.y = w0 * b2f(u0.z >> 16)    + w1 * b2f(u1.z >> 16);
    r1.z = w0 * b2f(u0.w & 0xffff) + w1 * b2f(u1.w & 0xffff);
    r1.w = w0 * b2f(u0.w >> 16)    + w1 * b2f(u1.w >> 16);
    *(float4*)o       = r0;
    *((float4*)o + 1) = r1;
}

// ---------------- workspace layout (total ~927 MB; identical to r0 layout) ----------------

constexpr size_t AL(size_t x) { return (x + 255) & ~(size_t)255; }
constexpr size_t OFF_XB     = 0;
constexpr size_t OFF_W1B    = OFF_XB   + AL((size_t)(BATCH + 1) * DIN * 2);
constexpr size_t OFF_W2B    = OFF_W1B  + AL((size_t)NEXP * DHID * DIN * 2);
constexpr size_t OFF_H      = OFF_W2B  + AL((size_t)NEXP * DOUT * DHID * 2);
constexpr size_t OFF_Y      = OFF_H    + AL((size_t)SLOTCAP * DHID * 2);
constexpr size_t OFF_TOKE   = OFF_Y    + AL((size_t)SLOTCAP * DOUT * 2);
constexpr size_t OFF_TOKW   = OFF_TOKE + AL((size_t)BATCH * 2 * 4);
constexpr size_t OFF_TSLOT  = OFF_TOKW + AL((size_t)BATCH * 2 * 4);
constexpr size_t OFF_SLOTTOK= OFF_TSLOT + AL((size_t)BATCH * 2 * 4);
constexpr size_t OFF_COUNTS = OFF_SLOTTOK + AL((size_t)SLOTCAP * 4);
constexpr size_t OFF_CURS   = OFF_COUNTS + 256;   /* NEXP*CNTSTR*4 == 256 */
constexpr size_t OFF_SEG    = OFF_CURS + 256;     /* NEXP*CNTSTR*4 == 256 */
constexpr size_t OFF_TILEE  = OFF_SEG + 256;
constexpr size_t OFF_TILER  = OFF_TILEE + AL(MAXTILES * 4);
constexpr size_t WS_NEEDED  = OFF_TILER + AL(MAXTILES * 4);

extern "C" void kernel_launch(void* const* d_in, const int* in_sizes, int n_in,
                              void* d_out, int out_size, void* d_ws, size_t ws_size,
                              hipStream_t stream) {
    const float* x  = (const float*)d_in[0];
    const float* gw = (const float*)d_in[1];
    const float* w1 = (const float*)d_in[2];
    const float* b1 = (const float*)d_in[3];
    const float* w2 = (const float*)d_in[4];
    const float* b2 = (const float*)d_in[5];
    float* out = (float*)d_out;
    char* ws = (char*)d_ws;

    u16*   xb      = (u16*)(ws + OFF_XB);
    u16*   w1b     = (u16*)(ws + OFF_W1B);
    u16*   w2b     = (u16*)(ws + OFF_W2B);
    u16*   hbuf    = (u16*)(ws + OFF_H);
    u16*   ybuf    = (u16*)(ws + OFF_Y);
    int*   toke    = (int*)(ws + OFF_TOKE);
    float* tokw    = (float*)(ws + OFF_TOKW);
    int*   tslot   = (int*)(ws + OFF_TSLOT);
    int*   slottok = (int*)(ws + OFF_SLOTTOK);
    int*   counts  = (int*)(ws + OFF_COUNTS);
    int*   curs    = (int*)(ws + OFF_CURS);
    int*   seg     = (int*)(ws + OFF_SEG);
    int*   tile_e  = (int*)(ws + OFF_TILEE);
    int*   tile_r  = (int*)(ws + OFF_TILER);

    hipMemsetAsync(counts, 0, NEXP * CNTSTR * sizeof(int), stream);

    // router also emits xb (fused convert_x) and block-aggregated counts
    router_kernel<<<512, 256, 0, stream>>>(x, gw, toke, tokw, counts, xb);
    convert_w_kernel<<<(int)((size_t)NEXP * DHID * DIN / (256 * 8)), 256, 0, stream>>>(w1, w1b);
    convert_w_kernel<<<(int)((size_t)NEXP * DOUT * DHID / (256 * 8)), 256, 0, stream>>>(w2, w2b);
    plan_kernel<<<1, 256, 0, stream>>>(counts, seg, tile_e, tile_r, curs, slottok);
    scatter_kernel<<<BATCH / 256, 256, 0, stream>>>(toke, curs, seg, slottok, tslot);

    // GEMM1: h[slot] = gelu(x[tok] . w1[e]^T + b1[e]);  M tiles x N tiles = 136 x 64
    gemm_kernel<DIN, DHID, true><<<dim3(DHID / 128, MAXTILES), 256, 0, stream>>>(
        xb, w1b, b1, tile_e, tile_r, slottok, hbuf);
    // GEMM2: y[slot] = h[slot] . w2[e]^T + b2[e];       136 x 16
    gemm_kernel<DHID, DOUT, false><<<dim3(DOUT / 128, MAXTILES), 256, 0, stream>>>(
        hbuf, w2b, b2, tile_e, tile_r, slottok, ybuf);

    combine_kernel<<<BATCH * DOUT / (256 * 8), 256, 0, stream>>>(ybuf, tslot, tokw, out);
}